// Round 7
// baseline (1129.888 us; speedup 1.0000x reference)
//
#include <hip/hip_runtime.h>
#include <cstdint>
#include <cmath>

// HashEncoderHyFluid round 12: resubmit of r11 (container infra flake, no
// data; source re-audited: no OOB/hang possible, 17.5KB LDS, capture-safe).
// r10 confirmed: gather-core is request-throughput bound (~1.49 cyc/line,
// 3rd consistent measurement; VGPR/occupancy insensitive). Split-pipeline
// traffic audit: 619MB gather FETCH = ~360MB table fills (8 XCDs x 45MB,
// structural) + ~250MB coord re-reads (16 rows x 16MB); plus 256MB ws
// round-trip + 32MB csrt. Fusion removes everything but the table fills:
// thread = one sorted query; perm-indirect coord read (1M random lines vs
// 4M coalesced); 16 scales in two 8-scale halves staged in LDS (17.5KB,
// no occupancy loss); 4 lanes emit each query's 64B output chunk per half
// via perm (nontemporal). Compute is bit-identical to r10 gather.
// Pipeline: memset(hist) -> histogram -> scan(writes cur) -> scatter(perm)
//        -> gather_fused (sorted order, scale-serial, LDS out-stage).

#define NSCALES 16
#define TPB 256
#define BINS 65536
#define QPB 128   // queries per transpose block (fallback path)

struct Cfg {
  float    res[NSCALES][4];
  uint32_t key[NSCALES][4];
  uint32_t mask[NSCALES];
  int      offset[NSCALES];
  int      dense[NSCALES];
};

typedef float v4f __attribute__((ext_vector_type(4)));
typedef float v2f __attribute__((ext_vector_type(2)));

__device__ __forceinline__ uint32_t bucket_key(float x, float y, float z, float w)
{
  uint32_t bx = (uint32_t)(x * 16.f); bx = bx > 15u ? 15u : bx;
  uint32_t by = (uint32_t)(y * 16.f); by = by > 15u ? 15u : by;
  uint32_t bz = (uint32_t)(z * 16.f); bz = bz > 15u ? 15u : bz;
  uint32_t bt = (uint32_t)(w * 16.f); bt = bt > 15u ? 15u : bt;
  uint32_t k = 0;
#pragma unroll
  for (int b = 0; b < 4; ++b) {
    k |= ((bx >> b) & 1u) << (4 * b + 0);
    k |= ((by >> b) & 1u) << (4 * b + 1);
    k |= ((bz >> b) & 1u) << (4 * b + 2);
    k |= ((bt >> b) & 1u) << (4 * b + 3);
  }
  return k;
}

// ---------------- sort phase ----------------
__global__ __launch_bounds__(TPB) void hist_kernel(
    const float* __restrict__ xyzt, uint32_t* __restrict__ hist, int N)
{
  const int i = blockIdx.x * TPB + threadIdx.x;
  if (i >= N) return;
  const v4f c = *(reinterpret_cast<const v4f*>(xyzt) + i);
  atomicAdd(&hist[bucket_key(c.x, c.y, c.z, c.w)], 1u);
}

// exclusive scan of hist -> cur (cur then serves as the atomic cursor)
__global__ __launch_bounds__(1024) void scan_kernel(
    const uint32_t* __restrict__ hist, uint32_t* __restrict__ cur)
{
  __shared__ uint32_t part[1024];
  const int t = threadIdx.x;
  const int base = t * (BINS / 1024);
  uint32_t s = 0;
  for (int j = 0; j < BINS / 1024; ++j) s += hist[base + j];
  part[t] = s;
  __syncthreads();
  for (int off = 1; off < 1024; off <<= 1) {
    uint32_t v = (t >= off) ? part[t - off] : 0u;
    __syncthreads();
    part[t] += v;
    __syncthreads();
  }
  uint32_t run = part[t] - s;   // exclusive prefix of this chunk
  for (int j = 0; j < BINS / 1024; ++j) {
    cur[base + j] = run;
    run += hist[base + j];
  }
}

// perm only: sorted position -> original query index
__global__ __launch_bounds__(TPB) void scatter_kernel(
    const float* __restrict__ xyzt,
    uint32_t* __restrict__ cur,
    uint32_t* __restrict__ perm, int N)
{
  const int i = blockIdx.x * TPB + threadIdx.x;
  if (i >= N) return;
  const v4f c = *(reinterpret_cast<const v4f*>(xyzt) + i);
  const uint32_t k = bucket_key(c.x, c.y, c.z, c.w);
  const uint32_t pos = atomicAdd(&cur[k], 1u);
  perm[pos] = (uint32_t)i;
}

// ---------------- fused gather + transpose ----------------
// thread = one sorted query. Coords via perm indirection (1 random 16B read
// per query). Scales processed in two halves of 8; each half staged in LDS
// then written as 4x16B chunks per query to out[perm[q]] (nontemporal).
__global__ __launch_bounds__(TPB) void gather_fused(
    const float*    __restrict__ xyzt,
    const float*    __restrict__ table,
    const uint32_t* __restrict__ perm,
    float*          __restrict__ out,
    int N, Cfg cfg)
{
  __shared__ float2   st[8][TPB + 1];
  __shared__ uint32_t pql[TPB];
  const int t  = threadIdx.x;
  const int q  = blockIdx.x * TPB + t;
  const int ql = q < N ? q : N - 1;
  const uint32_t pq = perm[ql];
  pql[t] = pq;
  const v4f c = *(reinterpret_cast<const v4f*>(xyzt) + pq);

#pragma unroll
  for (int half = 0; half < 2; ++half) {
#pragma unroll 1
    for (int si = 0; si < 8; ++si) {
      const int s = half * 8 + si;
      const float rx = cfg.res[s][0], ry = cfg.res[s][1];
      const float rz = cfg.res[s][2], rw = cfg.res[s][3];
      const uint32_t K0 = cfg.key[s][0], K1 = cfg.key[s][1];
      const uint32_t K2 = cfg.key[s][2], K3 = cfg.key[s][3];

      const float px = c.x * rx, py = c.y * ry, pz = c.z * rz, pw = c.w * rw;
      const float gx = floorf(px), gy = floorf(py);
      const float gz = floorf(pz), gw = floorf(pw);
      const float fx = px - gx, fy = py - gy, fz = pz - gz, fw = pw - gw;
      const uint32_t ix = (uint32_t)(int)gx, iy = (uint32_t)(int)gy;
      const uint32_t iz = (uint32_t)(int)gz, iw = (uint32_t)(int)gw;

      const uint32_t x0 = ix * K0, x1 = x0 + K0;
      const uint32_t y0 = iy * K1, y1 = y0 + K1;
      const uint32_t z0 = iz * K2, z1 = z0 + K2;
      const uint32_t u0 = iw * K3, u1 = u0 + K3;

      const float wx0 = 1.f - fx, wy0 = 1.f - fy;
      const float wz0 = 1.f - fz, ww0 = 1.f - fw;
      const float wA[4] = { wx0 * wy0, fx * wy0, wx0 * fy, fx * fy };
      const float wB[4] = { wz0 * ww0, fz * ww0, wz0 * fw, fz * fw };

      const float*  tbf = table + cfg.offset[s];
      const float2* __restrict__ tb  = reinterpret_cast<const float2*>(tbf);
      const float4* __restrict__ tb4 = reinterpret_cast<const float4*>(tbf);

      float a0 = 0.f, a1 = 0.f;
      if (cfg.dense[s]) {
        const uint32_t hA[4] = { x0 + y0, x1 + y0, x0 + y1, x1 + y1 };
        const uint32_t hB[4] = { z0 + u0, z1 + u0, z0 + u1, z1 + u1 };
#pragma unroll
        for (int i = 0; i < 16; ++i) {
          const uint32_t idx = hA[i & 3] + hB[i >> 2];
          const float2 v = tb[idx];
          const float w = wA[i & 3] * wB[i >> 2];
          a0 = fmaf(w, v.x, a0);
          a1 = fmaf(w, v.y, a1);
        }
      } else {
        const uint32_t msk = cfg.mask[s];
        if ((ix & 1u) == 0u) {
          // even ix: x-corner pair = {p, p^1} -> one aligned float4 each
          const uint32_t yv[2] = { y0, y1 };
          const uint32_t zw[4] = { z0 ^ u0, z1 ^ u0, z0 ^ u1, z1 ^ u1 };
#pragma unroll
          for (int j = 0; j < 8; ++j) {
            const int jy = j & 1, jz = j >> 1;
            const uint32_t p  = (x0 ^ yv[jy] ^ zw[jz]) & msk;
            const uint32_t e  = p & ~1u;
            const uint32_t sel = p & 1u;
            const float4 v = tb4[e >> 1];
            const float wlo = wA[2 * jy]     * wB[jz];
            const float whi = wA[2 * jy + 1] * wB[jz];
            const float l0 = sel ? v.z : v.x, l1 = sel ? v.w : v.y;
            const float h0 = sel ? v.x : v.z, h1 = sel ? v.y : v.w;
            a0 = fmaf(wlo, l0, fmaf(whi, h0, a0));
            a1 = fmaf(wlo, l1, fmaf(whi, h1, a1));
          }
        } else {
          const uint32_t hA[4] = { x0 ^ y0, x1 ^ y0, x0 ^ y1, x1 ^ y1 };
          const uint32_t hB[4] = { z0 ^ u0, z1 ^ u0, z0 ^ u1, z1 ^ u1 };
#pragma unroll
          for (int i = 0; i < 16; ++i) {
            const uint32_t idx = (hA[i & 3] ^ hB[i >> 2]) & msk;
            const float2 v = tb[idx];
            const float w = wA[i & 3] * wB[i >> 2];
            a0 = fmaf(w, v.x, a0);
            a1 = fmaf(w, v.y, a1);
          }
        }
      }
      st[si][t] = make_float2(a0, a1);
    }
    __syncthreads();
    // write phase: 4 lanes emit one query's 64B half-chunk (scales
    // half*8..half*8+7 -> out floats half*16..half*16+15)
#pragma unroll
    for (int i = 0; i < 4; ++i) {
      const int g  = i * TPB + t;   // 0..1023
      const int qi = g >> 2;
      const int h  = g & 3;
      if (blockIdx.x * TPB + qi < N) {
        const float2 a = st[2 * h][qi];
        const float2 b = st[2 * h + 1][qi];
        v4f val = { a.x, a.y, b.x, b.y };
        __builtin_nontemporal_store(
            val, (v4f*)(out + (size_t)pql[qi] * 32 + half * 16 + h * 4));
      }
    }
    __syncthreads();   // st reused by next half
  }
}

// ---------------- fallback: split gather (unsorted) + LDS transpose --------
__global__ __launch_bounds__(TPB) void gather_kernel(
    const float*  __restrict__ coords,
    const float*  __restrict__ table,
    float2*       __restrict__ ws,
    int N, int s_base, Cfg cfg)
{
  const int s = (int)blockIdx.y + s_base;
  const int q = blockIdx.x * TPB + threadIdx.x;
  if (q >= N) return;
  const v4f c = *(reinterpret_cast<const v4f*>(coords) + q);

  const float rx = cfg.res[s][0], ry = cfg.res[s][1];
  const float rz = cfg.res[s][2], rw = cfg.res[s][3];
  const uint32_t K0 = cfg.key[s][0], K1 = cfg.key[s][1];
  const uint32_t K2 = cfg.key[s][2], K3 = cfg.key[s][3];

  const float px = c.x * rx, py = c.y * ry, pz = c.z * rz, pw = c.w * rw;
  const float gx = floorf(px), gy = floorf(py), gz = floorf(pz), gw = floorf(pw);
  const float fx = px - gx, fy = py - gy, fz = pz - gz, fw = pw - gw;
  const uint32_t ix = (uint32_t)(int)gx, iy = (uint32_t)(int)gy;
  const uint32_t iz = (uint32_t)(int)gz, iw = (uint32_t)(int)gw;

  const uint32_t x0 = ix * K0, x1 = x0 + K0;
  const uint32_t y0 = iy * K1, y1 = y0 + K1;
  const uint32_t z0 = iz * K2, z1 = z0 + K2;
  const uint32_t u0 = iw * K3, u1 = u0 + K3;

  const float wx0 = 1.f - fx, wy0 = 1.f - fy, wz0 = 1.f - fz, ww0 = 1.f - fw;
  const float wA[4] = { wx0 * wy0, fx * wy0, wx0 * fy, fx * fy };
  const float wB[4] = { wz0 * ww0, fz * ww0, wz0 * fw, fz * fw };

  const float*  tbf = table + cfg.offset[s];
  const float2* __restrict__ tb  = reinterpret_cast<const float2*>(tbf);
  const float4* __restrict__ tb4 = reinterpret_cast<const float4*>(tbf);

  float a0 = 0.f, a1 = 0.f;
  if (cfg.dense[s]) {
    const uint32_t hA[4] = { x0 + y0, x1 + y0, x0 + y1, x1 + y1 };
    const uint32_t hB[4] = { z0 + u0, z1 + u0, z0 + u1, z1 + u1 };
#pragma unroll
    for (int i = 0; i < 16; ++i) {
      const uint32_t idx = hA[i & 3] + hB[i >> 2];
      const float2 v = tb[idx];
      const float w = wA[i & 3] * wB[i >> 2];
      a0 = fmaf(w, v.x, a0);
      a1 = fmaf(w, v.y, a1);
    }
  } else {
    const uint32_t msk = cfg.mask[s];
    if ((ix & 1u) == 0u) {
      const uint32_t yv[2] = { y0, y1 };
      const uint32_t zw[4] = { z0 ^ u0, z1 ^ u0, z0 ^ u1, z1 ^ u1 };
#pragma unroll
      for (int j = 0; j < 8; ++j) {
        const int jy = j & 1, jz = j >> 1;
        const uint32_t p  = (x0 ^ yv[jy] ^ zw[jz]) & msk;
        const uint32_t e  = p & ~1u;
        const uint32_t sel = p & 1u;
        const float4 v = tb4[e >> 1];
        const float wlo = wA[2 * jy]     * wB[jz];
        const float whi = wA[2 * jy + 1] * wB[jz];
        const float l0 = sel ? v.z : v.x, l1 = sel ? v.w : v.y;
        const float h0 = sel ? v.x : v.z, h1 = sel ? v.y : v.w;
        a0 = fmaf(wlo, l0, fmaf(whi, h0, a0));
        a1 = fmaf(wlo, l1, fmaf(whi, h1, a1));
      }
    } else {
      const uint32_t hA[4] = { x0 ^ y0, x1 ^ y0, x0 ^ y1, x1 ^ y1 };
      const uint32_t hB[4] = { z0 ^ u0, z1 ^ u0, z0 ^ u1, z1 ^ u1 };
#pragma unroll
      for (int i = 0; i < 16; ++i) {
        const uint32_t idx = (hA[i & 3] ^ hB[i >> 2]) & msk;
        const float2 v = tb[idx];
        const float w = wA[i & 3] * wB[i >> 2];
        a0 = fmaf(w, v.x, a0);
        a1 = fmaf(w, v.y, a1);
      }
    }
  }
  v2f val = { a0, a1 };
  __builtin_nontemporal_store(val, (v2f*)&ws[(size_t)s * N + q]);
}

__global__ __launch_bounds__(TPB) void transpose_kernel(
    const float2* __restrict__ ws,
    float*        __restrict__ out,
    int N)
{
  __shared__ float2 st[NSCALES][TPB + 1];
  const int t  = threadIdx.x;
  const int q  = blockIdx.x * TPB + t;
  const int ql = q < N ? q : N - 1;
#pragma unroll
  for (int s = 0; s < NSCALES; ++s)
    st[s][t] = ws[(size_t)s * N + ql];
  __syncthreads();
  const int base = blockIdx.x * (TPB * 2 * NSCALES);
#pragma unroll
  for (int it = 0; it < 8; ++it) {
    const int G  = it * 1024 + t * 4;
    const int qi = G >> 5;
    const int s0 = (G & 31) >> 1;
    if (blockIdx.x * TPB + qi < N) {
      const float2 a = st[s0][qi];
      const float2 b = st[s0 + 1][qi];
      v4f val = { a.x, a.y, b.x, b.y };
      __builtin_nontemporal_store(val, (v4f*)(out + base + G));
    }
  }
}

// ---------------- fallback: fused single-kernel (unsorted) ----------------
__global__ __launch_bounds__(TPB) void hashenc_fused(
    const float4* __restrict__ xyzt,
    const float*  __restrict__ table,
    float*        __restrict__ out,
    int N, Cfg cfg)
{
  __shared__ float2 st[NSCALES][TPB + 1];
  const int t  = threadIdx.x;
  const int q  = blockIdx.x * TPB + t;
  const int ql = q < N ? q : N - 1;
  const float4 c = xyzt[ql];
#pragma unroll 1
  for (int s = 0; s < NSCALES; ++s) {
    const float rx = cfg.res[s][0], ry = cfg.res[s][1];
    const float rz = cfg.res[s][2], rw = cfg.res[s][3];
    const uint32_t K0 = cfg.key[s][0], K1 = cfg.key[s][1];
    const uint32_t K2 = cfg.key[s][2], K3 = cfg.key[s][3];
    const float px = c.x * rx, py = c.y * ry, pz = c.z * rz, pw = c.w * rw;
    const float gx = floorf(px), gy = floorf(py), gz = floorf(pz), gw = floorf(pw);
    const float fx = px - gx, fy = py - gy, fz = pz - gz, fw = pw - gw;
    const uint32_t ix = (uint32_t)(int)gx, iy = (uint32_t)(int)gy;
    const uint32_t iz = (uint32_t)(int)gz, iw = (uint32_t)(int)gw;
    const uint32_t x0 = ix * K0, x1 = x0 + K0;
    const uint32_t y0 = iy * K1, y1 = y0 + K1;
    const uint32_t z0 = iz * K2, z1 = z0 + K2;
    const uint32_t u0 = iw * K3, u1 = u0 + K3;
    const float wx0 = 1.f - fx, wy0 = 1.f - fy, wz0 = 1.f - fz, ww0 = 1.f - fw;
    const float wA[4] = { wx0 * wy0, fx * wy0, wx0 * fy, fx * fy };
    const float wB[4] = { wz0 * ww0, fz * ww0, wz0 * fw, fz * fw };
    const float2* __restrict__ tb =
        reinterpret_cast<const float2*>(table + cfg.offset[s]);
    float a0 = 0.f, a1 = 0.f;
    if (cfg.dense[s]) {
      const uint32_t hA[4] = { x0 + y0, x1 + y0, x0 + y1, x1 + y1 };
      const uint32_t hB[4] = { z0 + u0, z1 + u0, z0 + u1, z1 + u1 };
#pragma unroll
      for (int i = 0; i < 16; ++i) {
        const uint32_t idx = hA[i & 3] + hB[i >> 2];
        const float2 v = tb[idx];
        const float w = wA[i & 3] * wB[i >> 2];
        a0 = fmaf(w, v.x, a0); a1 = fmaf(w, v.y, a1);
      }
    } else {
      const uint32_t msk = cfg.mask[s];
      const uint32_t hA[4] = { x0 ^ y0, x1 ^ y0, x0 ^ y1, x1 ^ y1 };
      const uint32_t hB[4] = { z0 ^ u0, z1 ^ u0, z0 ^ u1, z1 ^ u1 };
#pragma unroll
      for (int i = 0; i < 16; ++i) {
        const uint32_t idx = (hA[i & 3] ^ hB[i >> 2]) & msk;
        const float2 v = tb[idx];
        const float w = wA[i & 3] * wB[i >> 2];
        a0 = fmaf(w, v.x, a0); a1 = fmaf(w, v.y, a1);
      }
    }
    st[s][t] = make_float2(a0, a1);
  }
  __syncthreads();
  const int base = blockIdx.x * (TPB * 2 * NSCALES);
#pragma unroll
  for (int it = 0; it < 8; ++it) {
    const int G  = it * 1024 + t * 4;
    const int qi = G >> 5;
    const int s0 = (G & 31) >> 1;
    if (blockIdx.x * TPB + qi < N) {
      const float2 a = st[s0][qi];
      const float2 b = st[s0 + 1][qi];
      v4f val = { a.x, a.y, b.x, b.y };
      __builtin_nontemporal_store(val, (v4f*)(out + base + G));
    }
  }
}

// ---- host-side config, bit-exact replication of build_config() ----
static void build_cfg(Cfg& cfg)
{
  const double minr[4] = { 16.0, 16.0, 16.0, 16.0 };
  const double maxr[4] = { 256.0, 256.0, 256.0, 128.0 };
  const uint32_t primes[4] = { 1u, 2654435761u, 805459861u, 3674653429u };

  double b[4];
  for (int d = 0; d < 4; ++d)
    b[d] = ::exp((::log(maxr[d]) - ::log(minr[d])) / (double)(NSCALES - 1));

  long long total = 0;
  for (int s = 0; s < NSCALES; ++s) {
    long long res[4];
    for (int d = 0; d < 4; ++d)
      res[d] = (long long)::ceil(minr[d] * ::pow(b[d], (double)s));

    const long long raw =
        (res[0] + 1) * (res[1] + 1) * (res[2] + 1) * (res[3] + 1);
    long long p = (raw % 8 == 0) ? raw : ((raw + 7) / 8) * 8;
    if (p > 524288) p = 524288;
    const int ind = (raw <= p) ? 1 : 0;

    for (int d = 0; d < 4; ++d) cfg.res[s][d] = (float)res[d];
    if (ind) {
      cfg.key[s][0] = 1u;
      cfg.key[s][1] = (uint32_t)(res[0] + 1);
      cfg.key[s][2] = (uint32_t)((res[0] + 1) * (res[1] + 1));
      cfg.key[s][3] = (uint32_t)((res[0] + 1) * (res[1] + 1) * (res[2] + 1));
    } else {
      for (int d = 0; d < 4; ++d) cfg.key[s][d] = primes[d];
    }
    cfg.mask[s]   = (uint32_t)(p - 1);
    cfg.offset[s] = (int)total;
    cfg.dense[s]  = ind;
    total += p * 2;
  }
}

static inline size_t align_up(size_t v, size_t a) { return (v + a - 1) & ~(a - 1); }

extern "C" void kernel_launch(void* const* d_in, const int* in_sizes, int n_in,
                              void* d_out, int out_size, void* d_ws, size_t ws_size,
                              hipStream_t stream)
{
  const float* xyzt  = (const float*)d_in[0];
  const float* table = (const float*)d_in[1];
  float*       out   = (float*)d_out;
  const int N = in_sizes[0] / 4;

  Cfg cfg;
  build_cfg(cfg);

  const int qblocks = (N + TPB - 1) / TPB;

  // workspace layout
  size_t off = 0;
  const size_t perm_off = off;             off = align_up(off + (size_t)N * 4, 256);
  const size_t hist_off = off;             off = align_up(off + (size_t)BINS * 4, 256);
  const size_t cur_off  = off;             off = align_up(off + (size_t)BINS * 4, 256);
  const size_t need_sorted = off;
  const size_t need_plain  = (size_t)N * NSCALES * sizeof(float2);

  char* wsb = (char*)d_ws;

  if (ws_size >= need_sorted) {
    uint32_t* perm = (uint32_t*)(wsb + perm_off);
    uint32_t* hist = (uint32_t*)(wsb + hist_off);
    uint32_t* cur  = (uint32_t*)(wsb + cur_off);

    hipMemsetAsync(hist, 0, (size_t)BINS * 4, stream);
    hipLaunchKernelGGL(hist_kernel, dim3(qblocks), dim3(TPB), 0, stream,
                       xyzt, hist, N);
    hipLaunchKernelGGL(scan_kernel, dim3(1), dim3(1024), 0, stream, hist, cur);
    hipLaunchKernelGGL(scatter_kernel, dim3(qblocks), dim3(TPB), 0, stream,
                       xyzt, cur, perm, N);
    hipLaunchKernelGGL(gather_fused, dim3(qblocks), dim3(TPB), 0, stream,
                       xyzt, table, perm, out, N, cfg);
  } else if (ws_size >= need_plain) {
    float2* ws = (float2*)d_ws;
    hipLaunchKernelGGL(gather_kernel, dim3(qblocks, NSCALES), dim3(TPB), 0,
                       stream, xyzt, table, ws, N, 0, cfg);
    hipLaunchKernelGGL(transpose_kernel, dim3(qblocks), dim3(TPB), 0,
                       stream, ws, out, N);
  } else {
    hipLaunchKernelGGL(hashenc_fused, dim3(qblocks), dim3(TPB), 0,
                       stream, (const float4*)xyzt, table, out, N, cfg);
  }
}

// Round 8
// 833.682 us; speedup vs baseline: 1.3553x; 1.3553x over previous
//
#include <hip/hip_runtime.h>
#include <cstdint>
#include <cmath>

// HashEncoderHyFluid round 13: sort-value A/B — drop the sort entirely.
// r12 refuted fusion decisively: scale-serial-per-block -> concurrent blocks
// span all 16 tables -> 45MB hashed tables thrash 4MB/XCD L2 -> FETCH 619MB
// -> 3.1GB, 880us. The split grid (qblocks,16) works because dispatch order
// keeps in-flight blocks within ~2 adjacent scales (tables L2-resident).
// Open question: sort's benefit to the SPLIT gather was never isolated.
// Cost is measured: sort+perm-transpose = 314us of 809. Request model says
// unsorted split gather ~= +25% (extra unique lines at low scales, L2-hit
// requests). If unsorted gather ~600-650us, 2-dispatch plain path wins.
// Pipeline: gather16 (original coords, scale-major grid, NT ws stores)
//        -> LDS transpose (no perm, NT ws reads, coalesced out writes).
// Pre-commit: if total >= 809, revert to r10 sort pipeline = final.

#define NSCALES 16
#define TPB 256

struct Cfg {
  float    res[NSCALES][4];
  uint32_t key[NSCALES][4];
  uint32_t mask[NSCALES];
  int      offset[NSCALES];
  int      dense[NSCALES];
};

typedef float v4f __attribute__((ext_vector_type(4)));
typedef float v2f __attribute__((ext_vector_type(2)));

// ---------------- gather: per-scale, scale = slow grid dim ----------------
__global__ __launch_bounds__(TPB) void gather_kernel(
    const float*  __restrict__ coords,
    const float*  __restrict__ table,
    float2*       __restrict__ ws,
    int N, int s_base, Cfg cfg)
{
  const int s = (int)blockIdx.y + s_base;
  const int q = blockIdx.x * TPB + threadIdx.x;
  if (q >= N) return;
  const v4f c = *(reinterpret_cast<const v4f*>(coords) + q);

  const float rx = cfg.res[s][0], ry = cfg.res[s][1];
  const float rz = cfg.res[s][2], rw = cfg.res[s][3];
  const uint32_t K0 = cfg.key[s][0], K1 = cfg.key[s][1];
  const uint32_t K2 = cfg.key[s][2], K3 = cfg.key[s][3];

  const float px = c.x * rx, py = c.y * ry, pz = c.z * rz, pw = c.w * rw;
  const float gx = floorf(px), gy = floorf(py), gz = floorf(pz), gw = floorf(pw);
  const float fx = px - gx, fy = py - gy, fz = pz - gz, fw = pw - gw;
  const uint32_t ix = (uint32_t)(int)gx, iy = (uint32_t)(int)gy;
  const uint32_t iz = (uint32_t)(int)gz, iw = (uint32_t)(int)gw;

  const uint32_t x0 = ix * K0, x1 = x0 + K0;
  const uint32_t y0 = iy * K1, y1 = y0 + K1;
  const uint32_t z0 = iz * K2, z1 = z0 + K2;
  const uint32_t u0 = iw * K3, u1 = u0 + K3;

  const float wx0 = 1.f - fx, wy0 = 1.f - fy, wz0 = 1.f - fz, ww0 = 1.f - fw;
  const float wA[4] = { wx0 * wy0, fx * wy0, wx0 * fy, fx * fy };
  const float wB[4] = { wz0 * ww0, fz * ww0, wz0 * fw, fz * fw };

  const float*  tbf = table + cfg.offset[s];
  const float2* __restrict__ tb  = reinterpret_cast<const float2*>(tbf);
  const float4* __restrict__ tb4 = reinterpret_cast<const float4*>(tbf);

  float a0 = 0.f, a1 = 0.f;
  if (cfg.dense[s]) {
    const uint32_t hA[4] = { x0 + y0, x1 + y0, x0 + y1, x1 + y1 };
    const uint32_t hB[4] = { z0 + u0, z1 + u0, z0 + u1, z1 + u1 };
#pragma unroll
    for (int i = 0; i < 16; ++i) {
      const uint32_t idx = hA[i & 3] + hB[i >> 2];
      const float2 v = tb[idx];
      const float w = wA[i & 3] * wB[i >> 2];
      a0 = fmaf(w, v.x, a0);
      a1 = fmaf(w, v.y, a1);
    }
  } else {
    const uint32_t msk = cfg.mask[s];
    if ((ix & 1u) == 0u) {
      // even ix: x-corner pair = {p, p^1} -> one aligned float4 each
      const uint32_t yv[2] = { y0, y1 };
      const uint32_t zw[4] = { z0 ^ u0, z1 ^ u0, z0 ^ u1, z1 ^ u1 };
#pragma unroll
      for (int j = 0; j < 8; ++j) {
        const int jy = j & 1, jz = j >> 1;
        const uint32_t p  = (x0 ^ yv[jy] ^ zw[jz]) & msk;
        const uint32_t e  = p & ~1u;
        const uint32_t sel = p & 1u;
        const float4 v = tb4[e >> 1];
        const float wlo = wA[2 * jy]     * wB[jz];
        const float whi = wA[2 * jy + 1] * wB[jz];
        const float l0 = sel ? v.z : v.x, l1 = sel ? v.w : v.y;
        const float h0 = sel ? v.x : v.z, h1 = sel ? v.y : v.w;
        a0 = fmaf(wlo, l0, fmaf(whi, h0, a0));
        a1 = fmaf(wlo, l1, fmaf(whi, h1, a1));
      }
    } else {
      const uint32_t hA[4] = { x0 ^ y0, x1 ^ y0, x0 ^ y1, x1 ^ y1 };
      const uint32_t hB[4] = { z0 ^ u0, z1 ^ u0, z0 ^ u1, z1 ^ u1 };
#pragma unroll
      for (int i = 0; i < 16; ++i) {
        const uint32_t idx = (hA[i & 3] ^ hB[i >> 2]) & msk;
        const float2 v = tb[idx];
        const float w = wA[i & 3] * wB[i >> 2];
        a0 = fmaf(w, v.x, a0);
        a1 = fmaf(w, v.y, a1);
      }
    }
  }
  // nontemporal: keep the 128MB ws stream out of L2 (tables must stay hot)
  v2f val = { a0, a1 };
  __builtin_nontemporal_store(val, (v2f*)&ws[(size_t)s * N + q]);
}

// ---------------- LDS transpose (no perm) ----------------
// ws is in original query order; out writes fully coalesced per block.
__global__ __launch_bounds__(TPB) void transpose_kernel(
    const float2* __restrict__ ws,
    float*        __restrict__ out,
    int N)
{
  __shared__ float2 st[NSCALES][TPB + 1];
  const int t  = threadIdx.x;
  const int q  = blockIdx.x * TPB + t;
  const int ql = q < N ? q : N - 1;
#pragma unroll
  for (int s = 0; s < NSCALES; ++s) {
    const v2f tmp = __builtin_nontemporal_load(
        reinterpret_cast<const v2f*>(&ws[(size_t)s * N + ql]));
    st[s][t] = make_float2(tmp.x, tmp.y);
  }
  __syncthreads();
  const int base = blockIdx.x * (TPB * 2 * NSCALES);
#pragma unroll
  for (int it = 0; it < 8; ++it) {
    const int G  = it * 1024 + t * 4;
    const int qi = G >> 5;
    const int s0 = (G & 31) >> 1;
    if (blockIdx.x * TPB + qi < N) {
      const float2 a = st[s0][qi];
      const float2 b = st[s0 + 1][qi];
      v4f val = { a.x, a.y, b.x, b.y };
      __builtin_nontemporal_store(val, (v4f*)(out + base + G));
    }
  }
}

// ---------------- fallback: fused single-kernel (if ws tiny) ----------------
__global__ __launch_bounds__(TPB) void hashenc_fused(
    const float4* __restrict__ xyzt,
    const float*  __restrict__ table,
    float*        __restrict__ out,
    int N, Cfg cfg)
{
  __shared__ float2 st[NSCALES][TPB + 1];
  const int t  = threadIdx.x;
  const int q  = blockIdx.x * TPB + t;
  const int ql = q < N ? q : N - 1;
  const float4 c = xyzt[ql];
#pragma unroll 1
  for (int s = 0; s < NSCALES; ++s) {
    const float rx = cfg.res[s][0], ry = cfg.res[s][1];
    const float rz = cfg.res[s][2], rw = cfg.res[s][3];
    const uint32_t K0 = cfg.key[s][0], K1 = cfg.key[s][1];
    const uint32_t K2 = cfg.key[s][2], K3 = cfg.key[s][3];
    const float px = c.x * rx, py = c.y * ry, pz = c.z * rz, pw = c.w * rw;
    const float gx = floorf(px), gy = floorf(py), gz = floorf(pz), gw = floorf(pw);
    const float fx = px - gx, fy = py - gy, fz = pz - gz, fw = pw - gw;
    const uint32_t ix = (uint32_t)(int)gx, iy = (uint32_t)(int)gy;
    const uint32_t iz = (uint32_t)(int)gz, iw = (uint32_t)(int)gw;
    const uint32_t x0 = ix * K0, x1 = x0 + K0;
    const uint32_t y0 = iy * K1, y1 = y0 + K1;
    const uint32_t z0 = iz * K2, z1 = z0 + K2;
    const uint32_t u0 = iw * K3, u1 = u0 + K3;
    const float wx0 = 1.f - fx, wy0 = 1.f - fy, wz0 = 1.f - fz, ww0 = 1.f - fw;
    const float wA[4] = { wx0 * wy0, fx * wy0, wx0 * fy, fx * fy };
    const float wB[4] = { wz0 * ww0, fz * ww0, wz0 * fw, fz * fw };
    const float2* __restrict__ tb =
        reinterpret_cast<const float2*>(table + cfg.offset[s]);
    float a0 = 0.f, a1 = 0.f;
    if (cfg.dense[s]) {
      const uint32_t hA[4] = { x0 + y0, x1 + y0, x0 + y1, x1 + y1 };
      const uint32_t hB[4] = { z0 + u0, z1 + u0, z0 + u1, z1 + u1 };
#pragma unroll
      for (int i = 0; i < 16; ++i) {
        const uint32_t idx = hA[i & 3] + hB[i >> 2];
        const float2 v = tb[idx];
        const float w = wA[i & 3] * wB[i >> 2];
        a0 = fmaf(w, v.x, a0); a1 = fmaf(w, v.y, a1);
      }
    } else {
      const uint32_t msk = cfg.mask[s];
      const uint32_t hA[4] = { x0 ^ y0, x1 ^ y0, x0 ^ y1, x1 ^ y1 };
      const uint32_t hB[4] = { z0 ^ u0, z1 ^ u0, z0 ^ u1, z1 ^ u1 };
#pragma unroll
      for (int i = 0; i < 16; ++i) {
        const uint32_t idx = (hA[i & 3] ^ hB[i >> 2]) & msk;
        const float2 v = tb[idx];
        const float w = wA[i & 3] * wB[i >> 2];
        a0 = fmaf(w, v.x, a0); a1 = fmaf(w, v.y, a1);
      }
    }
    st[s][t] = make_float2(a0, a1);
  }
  __syncthreads();
  const int base = blockIdx.x * (TPB * 2 * NSCALES);
#pragma unroll
  for (int it = 0; it < 8; ++it) {
    const int G  = it * 1024 + t * 4;
    const int qi = G >> 5;
    const int s0 = (G & 31) >> 1;
    if (blockIdx.x * TPB + qi < N) {
      const float2 a = st[s0][qi];
      const float2 b = st[s0 + 1][qi];
      v4f val = { a.x, a.y, b.x, b.y };
      __builtin_nontemporal_store(val, (v4f*)(out + base + G));
    }
  }
}

// ---- host-side config, bit-exact replication of build_config() ----
static void build_cfg(Cfg& cfg)
{
  const double minr[4] = { 16.0, 16.0, 16.0, 16.0 };
  const double maxr[4] = { 256.0, 256.0, 256.0, 128.0 };
  const uint32_t primes[4] = { 1u, 2654435761u, 805459861u, 3674653429u };

  double b[4];
  for (int d = 0; d < 4; ++d)
    b[d] = ::exp((::log(maxr[d]) - ::log(minr[d])) / (double)(NSCALES - 1));

  long long total = 0;
  for (int s = 0; s < NSCALES; ++s) {
    long long res[4];
    for (int d = 0; d < 4; ++d)
      res[d] = (long long)::ceil(minr[d] * ::pow(b[d], (double)s));

    const long long raw =
        (res[0] + 1) * (res[1] + 1) * (res[2] + 1) * (res[3] + 1);
    long long p = (raw % 8 == 0) ? raw : ((raw + 7) / 8) * 8;
    if (p > 524288) p = 524288;
    const int ind = (raw <= p) ? 1 : 0;

    for (int d = 0; d < 4; ++d) cfg.res[s][d] = (float)res[d];
    if (ind) {
      cfg.key[s][0] = 1u;
      cfg.key[s][1] = (uint32_t)(res[0] + 1);
      cfg.key[s][2] = (uint32_t)((res[0] + 1) * (res[1] + 1));
      cfg.key[s][3] = (uint32_t)((res[0] + 1) * (res[1] + 1) * (res[2] + 1));
    } else {
      for (int d = 0; d < 4; ++d) cfg.key[s][d] = primes[d];
    }
    cfg.mask[s]   = (uint32_t)(p - 1);
    cfg.offset[s] = (int)total;
    cfg.dense[s]  = ind;
    total += p * 2;
  }
}

extern "C" void kernel_launch(void* const* d_in, const int* in_sizes, int n_in,
                              void* d_out, int out_size, void* d_ws, size_t ws_size,
                              hipStream_t stream)
{
  const float* xyzt  = (const float*)d_in[0];
  const float* table = (const float*)d_in[1];
  float*       out   = (float*)d_out;
  const int N = in_sizes[0] / 4;

  Cfg cfg;
  build_cfg(cfg);

  const int qblocks = (N + TPB - 1) / TPB;
  const size_t need_plain = (size_t)N * NSCALES * sizeof(float2);

  if (ws_size >= need_plain) {
    float2* ws = (float2*)d_ws;
    hipLaunchKernelGGL(gather_kernel, dim3(qblocks, NSCALES), dim3(TPB), 0,
                       stream, xyzt, table, ws, N, 0, cfg);
    hipLaunchKernelGGL(transpose_kernel, dim3(qblocks), dim3(TPB), 0,
                       stream, ws, out, N);
  } else {
    hipLaunchKernelGGL(hashenc_fused, dim3(qblocks), dim3(TPB), 0,
                       stream, (const float4*)xyzt, table, out, N, cfg);
  }
}

// Round 9
// 808.552 us; speedup vs baseline: 1.3974x; 1.0311x over previous
//
#include <hip/hip_runtime.h>
#include <cstdint>
#include <cmath>

// HashEncoderHyFluid round 14: FINAL — revert to r10 (best measured: 809us).
// r13 closed the last open A/B: unsorted split gather = 677us/781MB vs
// sorted 495us/619MB; sort+perm-transpose cost < its 182us gather benefit.
// All structural alternatives measured and refuted: bucket-LDS staging
// (r6 +224us), MLP restructure (r7 null), cache-allocating ws stores
// (r7 +13us), full per-block fusion (r12 +320us, L2 table thrash 5x FETCH),
// no-sort (r13 +24us). Gather core is at a reproducible ~1.49 cyc/unique-
// line L2-request-throughput floor (~204 req/query, 3x reproduced 494-496us,
// insensitive to VGPR/occupancy/order) — not HBM (19%) nor VALU (18%).
// Pipeline: memset(hist) -> histogram -> scan(writes cur) -> scatter(perm,
// c_sorted) -> gather16 (sorted coords, scale-major grid) -> LDS transpose+perm.

#define NSCALES 16
#define TPB 256
#define BINS 65536
#define QPB 128   // queries per transpose block

struct Cfg {
  float    res[NSCALES][4];
  uint32_t key[NSCALES][4];
  uint32_t mask[NSCALES];
  int      offset[NSCALES];
  int      dense[NSCALES];
};

typedef float v4f __attribute__((ext_vector_type(4)));
typedef float v2f __attribute__((ext_vector_type(2)));

__device__ __forceinline__ uint32_t bucket_key(float x, float y, float z, float w)
{
  uint32_t bx = (uint32_t)(x * 16.f); bx = bx > 15u ? 15u : bx;
  uint32_t by = (uint32_t)(y * 16.f); by = by > 15u ? 15u : by;
  uint32_t bz = (uint32_t)(z * 16.f); bz = bz > 15u ? 15u : bz;
  uint32_t bt = (uint32_t)(w * 16.f); bt = bt > 15u ? 15u : bt;
  uint32_t k = 0;
#pragma unroll
  for (int b = 0; b < 4; ++b) {
    k |= ((bx >> b) & 1u) << (4 * b + 0);
    k |= ((by >> b) & 1u) << (4 * b + 1);
    k |= ((bz >> b) & 1u) << (4 * b + 2);
    k |= ((bt >> b) & 1u) << (4 * b + 3);
  }
  return k;
}

// ---------------- sort phase ----------------
__global__ __launch_bounds__(TPB) void hist_kernel(
    const float* __restrict__ xyzt, uint32_t* __restrict__ hist, int N)
{
  const int i = blockIdx.x * TPB + threadIdx.x;
  if (i >= N) return;
  const v4f c = *(reinterpret_cast<const v4f*>(xyzt) + i);
  atomicAdd(&hist[bucket_key(c.x, c.y, c.z, c.w)], 1u);
}

// exclusive scan of hist -> cur (cur then serves as the atomic cursor)
__global__ __launch_bounds__(1024) void scan_kernel(
    const uint32_t* __restrict__ hist, uint32_t* __restrict__ cur)
{
  __shared__ uint32_t part[1024];
  const int t = threadIdx.x;
  const int base = t * (BINS / 1024);
  uint32_t s = 0;
  for (int j = 0; j < BINS / 1024; ++j) s += hist[base + j];
  part[t] = s;
  __syncthreads();
  for (int off = 1; off < 1024; off <<= 1) {
    uint32_t v = (t >= off) ? part[t - off] : 0u;
    __syncthreads();
    part[t] += v;
    __syncthreads();
  }
  uint32_t run = part[t] - s;   // exclusive prefix of this chunk
  for (int j = 0; j < BINS / 1024; ++j) {
    cur[base + j] = run;
    run += hist[base + j];
  }
}

__global__ __launch_bounds__(TPB) void scatter_kernel(
    const float* __restrict__ xyzt,
    uint32_t* __restrict__ cur,
    uint32_t* __restrict__ perm, float* __restrict__ c_sorted, int N)
{
  const int i = blockIdx.x * TPB + threadIdx.x;
  if (i >= N) return;
  const v4f c = *(reinterpret_cast<const v4f*>(xyzt) + i);
  const uint32_t k = bucket_key(c.x, c.y, c.z, c.w);
  const uint32_t pos = atomicAdd(&cur[k], 1u);
  perm[pos] = (uint32_t)i;
  *(reinterpret_cast<v4f*>(c_sorted) + pos) = c;
}

// ---------------- gather: per-scale, scale = slow grid dim ----------------
__global__ __launch_bounds__(TPB) void gather_kernel(
    const float*  __restrict__ coords,
    const float*  __restrict__ table,
    float2*       __restrict__ ws,
    int N, int s_base, Cfg cfg)
{
  const int s = (int)blockIdx.y + s_base;
  const int q = blockIdx.x * TPB + threadIdx.x;
  if (q >= N) return;
  const v4f c = *(reinterpret_cast<const v4f*>(coords) + q);

  const float rx = cfg.res[s][0], ry = cfg.res[s][1];
  const float rz = cfg.res[s][2], rw = cfg.res[s][3];
  const uint32_t K0 = cfg.key[s][0], K1 = cfg.key[s][1];
  const uint32_t K2 = cfg.key[s][2], K3 = cfg.key[s][3];

  const float px = c.x * rx, py = c.y * ry, pz = c.z * rz, pw = c.w * rw;
  const float gx = floorf(px), gy = floorf(py), gz = floorf(pz), gw = floorf(pw);
  const float fx = px - gx, fy = py - gy, fz = pz - gz, fw = pw - gw;
  const uint32_t ix = (uint32_t)(int)gx, iy = (uint32_t)(int)gy;
  const uint32_t iz = (uint32_t)(int)gz, iw = (uint32_t)(int)gw;

  const uint32_t x0 = ix * K0, x1 = x0 + K0;
  const uint32_t y0 = iy * K1, y1 = y0 + K1;
  const uint32_t z0 = iz * K2, z1 = z0 + K2;
  const uint32_t u0 = iw * K3, u1 = u0 + K3;

  const float wx0 = 1.f - fx, wy0 = 1.f - fy, wz0 = 1.f - fz, ww0 = 1.f - fw;
  const float wA[4] = { wx0 * wy0, fx * wy0, wx0 * fy, fx * fy };
  const float wB[4] = { wz0 * ww0, fz * ww0, wz0 * fw, fz * fw };

  const float*  tbf = table + cfg.offset[s];
  const float2* __restrict__ tb  = reinterpret_cast<const float2*>(tbf);
  const float4* __restrict__ tb4 = reinterpret_cast<const float4*>(tbf);

  float a0 = 0.f, a1 = 0.f;
  if (cfg.dense[s]) {
    const uint32_t hA[4] = { x0 + y0, x1 + y0, x0 + y1, x1 + y1 };
    const uint32_t hB[4] = { z0 + u0, z1 + u0, z0 + u1, z1 + u1 };
#pragma unroll
    for (int i = 0; i < 16; ++i) {
      const uint32_t idx = hA[i & 3] + hB[i >> 2];
      const float2 v = tb[idx];
      const float w = wA[i & 3] * wB[i >> 2];
      a0 = fmaf(w, v.x, a0);
      a1 = fmaf(w, v.y, a1);
    }
  } else {
    const uint32_t msk = cfg.mask[s];
    if ((ix & 1u) == 0u) {
      // even ix: x-corner pair = {p, p^1} -> one aligned float4 each
      const uint32_t yv[2] = { y0, y1 };
      const uint32_t zw[4] = { z0 ^ u0, z1 ^ u0, z0 ^ u1, z1 ^ u1 };
#pragma unroll
      for (int j = 0; j < 8; ++j) {
        const int jy = j & 1, jz = j >> 1;
        const uint32_t p  = (x0 ^ yv[jy] ^ zw[jz]) & msk;
        const uint32_t e  = p & ~1u;
        const uint32_t sel = p & 1u;
        const float4 v = tb4[e >> 1];
        const float wlo = wA[2 * jy]     * wB[jz];
        const float whi = wA[2 * jy + 1] * wB[jz];
        const float l0 = sel ? v.z : v.x, l1 = sel ? v.w : v.y;
        const float h0 = sel ? v.x : v.z, h1 = sel ? v.y : v.w;
        a0 = fmaf(wlo, l0, fmaf(whi, h0, a0));
        a1 = fmaf(wlo, l1, fmaf(whi, h1, a1));
      }
    } else {
      const uint32_t hA[4] = { x0 ^ y0, x1 ^ y0, x0 ^ y1, x1 ^ y1 };
      const uint32_t hB[4] = { z0 ^ u0, z1 ^ u0, z0 ^ u1, z1 ^ u1 };
#pragma unroll
      for (int i = 0; i < 16; ++i) {
        const uint32_t idx = (hA[i & 3] ^ hB[i >> 2]) & msk;
        const float2 v = tb[idx];
        const float w = wA[i & 3] * wB[i >> 2];
        a0 = fmaf(w, v.x, a0);
        a1 = fmaf(w, v.y, a1);
      }
    }
  }
  // nontemporal: keep the 128MB ws stream out of L2 (tables must stay hot)
  v2f val = { a0, a1 };
  __builtin_nontemporal_store(val, (v2f*)&ws[(size_t)s * N + q]);
}

// ---------------- LDS transpose + perm scatter ----------------
// block = QPB sorted queries. Stage ws coalesced per scale into LDS, then
// 8 lanes emit one query's 128B output chunk (coalesced random-base write).
__global__ __launch_bounds__(TPB) void transpose_perm(
    const float2*   __restrict__ ws,
    const uint32_t* __restrict__ perm,
    float*          __restrict__ out,
    int N)
{
  __shared__ float2 st[NSCALES][QPB + 1];
  const int t  = threadIdx.x;
  const int q0 = blockIdx.x * QPB;
#pragma unroll
  for (int i = 0; i < (NSCALES * QPB) / TPB; ++i) {   // 8 iters
    const int idx = i * TPB + t;          // 0..2047
    const int sc  = idx >> 7;             // idx / QPB
    const int qi  = idx & (QPB - 1);
    const int q   = q0 + qi;
    const v2f tmp = __builtin_nontemporal_load(
        reinterpret_cast<const v2f*>(&ws[(size_t)sc * N + (q < N ? q : N - 1)]));
    st[sc][qi] = make_float2(tmp.x, tmp.y);
  }
  __syncthreads();
#pragma unroll
  for (int i = 0; i < (QPB * 8) / TPB; ++i) {         // 4 iters
    const int g  = i * TPB + t;           // 0..1023
    const int qi = g >> 3;
    const int h  = g & 7;
    const int q  = q0 + qi;
    if (q < N) {
      const float2 a = st[2 * h][qi];
      const float2 b = st[2 * h + 1][qi];
      const uint32_t pq = perm[q];
      v4f val = { a.x, a.y, b.x, b.y };
      __builtin_nontemporal_store(val, (v4f*)(out + (size_t)pq * 32 + h * 4));
    }
  }
}

// ---------------- fallback phase-2: LDS transpose (no perm) ----------------
__global__ __launch_bounds__(TPB) void transpose_kernel(
    const float2* __restrict__ ws,
    float*        __restrict__ out,
    int N)
{
  __shared__ float2 st[NSCALES][TPB + 1];
  const int t  = threadIdx.x;
  const int q  = blockIdx.x * TPB + t;
  const int ql = q < N ? q : N - 1;
#pragma unroll
  for (int s = 0; s < NSCALES; ++s)
    st[s][t] = ws[(size_t)s * N + ql];
  __syncthreads();
  const int base = blockIdx.x * (TPB * 2 * NSCALES);
#pragma unroll
  for (int it = 0; it < 8; ++it) {
    const int G  = it * 1024 + t * 4;
    const int qi = G >> 5;
    const int s0 = (G & 31) >> 1;
    if (blockIdx.x * TPB + qi < N) {
      const float2 a = st[s0][qi];
      const float2 b = st[s0 + 1][qi];
      v4f val = { a.x, a.y, b.x, b.y };
      __builtin_nontemporal_store(val, (v4f*)(out + base + G));
    }
  }
}

// ---------------- fallback: fused single-kernel (if ws tiny) ----------------
__global__ __launch_bounds__(TPB) void hashenc_fused(
    const float4* __restrict__ xyzt,
    const float*  __restrict__ table,
    float*        __restrict__ out,
    int N, Cfg cfg)
{
  __shared__ float2 st[NSCALES][TPB + 1];
  const int t  = threadIdx.x;
  const int q  = blockIdx.x * TPB + t;
  const int ql = q < N ? q : N - 1;
  const float4 c = xyzt[ql];
#pragma unroll 1
  for (int s = 0; s < NSCALES; ++s) {
    const float rx = cfg.res[s][0], ry = cfg.res[s][1];
    const float rz = cfg.res[s][2], rw = cfg.res[s][3];
    const uint32_t K0 = cfg.key[s][0], K1 = cfg.key[s][1];
    const uint32_t K2 = cfg.key[s][2], K3 = cfg.key[s][3];
    const float px = c.x * rx, py = c.y * ry, pz = c.z * rz, pw = c.w * rw;
    const float gx = floorf(px), gy = floorf(py), gz = floorf(pz), gw = floorf(pw);
    const float fx = px - gx, fy = py - gy, fz = pz - gz, fw = pw - gw;
    const uint32_t ix = (uint32_t)(int)gx, iy = (uint32_t)(int)gy;
    const uint32_t iz = (uint32_t)(int)gz, iw = (uint32_t)(int)gw;
    const uint32_t x0 = ix * K0, x1 = x0 + K0;
    const uint32_t y0 = iy * K1, y1 = y0 + K1;
    const uint32_t z0 = iz * K2, z1 = z0 + K2;
    const uint32_t u0 = iw * K3, u1 = u0 + K3;
    const float wx0 = 1.f - fx, wy0 = 1.f - fy, wz0 = 1.f - fz, ww0 = 1.f - fw;
    const float wA[4] = { wx0 * wy0, fx * wy0, wx0 * fy, fx * fy };
    const float wB[4] = { wz0 * ww0, fz * ww0, wz0 * fw, fz * fw };
    const float2* __restrict__ tb =
        reinterpret_cast<const float2*>(table + cfg.offset[s]);
    float a0 = 0.f, a1 = 0.f;
    if (cfg.dense[s]) {
      const uint32_t hA[4] = { x0 + y0, x1 + y0, x0 + y1, x1 + y1 };
      const uint32_t hB[4] = { z0 + u0, z1 + u0, z0 + u1, z1 + u1 };
#pragma unroll
      for (int i = 0; i < 16; ++i) {
        const uint32_t idx = hA[i & 3] + hB[i >> 2];
        const float2 v = tb[idx];
        const float w = wA[i & 3] * wB[i >> 2];
        a0 = fmaf(w, v.x, a0); a1 = fmaf(w, v.y, a1);
      }
    } else {
      const uint32_t msk = cfg.mask[s];
      const uint32_t hA[4] = { x0 ^ y0, x1 ^ y0, x0 ^ y1, x1 ^ y1 };
      const uint32_t hB[4] = { z0 ^ u0, z1 ^ u0, z0 ^ u1, z1 ^ u1 };
#pragma unroll
      for (int i = 0; i < 16; ++i) {
        const uint32_t idx = (hA[i & 3] ^ hB[i >> 2]) & msk;
        const float2 v = tb[idx];
        const float w = wA[i & 3] * wB[i >> 2];
        a0 = fmaf(w, v.x, a0); a1 = fmaf(w, v.y, a1);
      }
    }
    st[s][t] = make_float2(a0, a1);
  }
  __syncthreads();
  const int base = blockIdx.x * (TPB * 2 * NSCALES);
#pragma unroll
  for (int it = 0; it < 8; ++it) {
    const int G  = it * 1024 + t * 4;
    const int qi = G >> 5;
    const int s0 = (G & 31) >> 1;
    if (blockIdx.x * TPB + qi < N) {
      const float2 a = st[s0][qi];
      const float2 b = st[s0 + 1][qi];
      v4f val = { a.x, a.y, b.x, b.y };
      __builtin_nontemporal_store(val, (v4f*)(out + base + G));
    }
  }
}

// ---- host-side config, bit-exact replication of build_config() ----
static void build_cfg(Cfg& cfg)
{
  const double minr[4] = { 16.0, 16.0, 16.0, 16.0 };
  const double maxr[4] = { 256.0, 256.0, 256.0, 128.0 };
  const uint32_t primes[4] = { 1u, 2654435761u, 805459861u, 3674653429u };

  double b[4];
  for (int d = 0; d < 4; ++d)
    b[d] = ::exp((::log(maxr[d]) - ::log(minr[d])) / (double)(NSCALES - 1));

  long long total = 0;
  for (int s = 0; s < NSCALES; ++s) {
    long long res[4];
    for (int d = 0; d < 4; ++d)
      res[d] = (long long)::ceil(minr[d] * ::pow(b[d], (double)s));

    const long long raw =
        (res[0] + 1) * (res[1] + 1) * (res[2] + 1) * (res[3] + 1);
    long long p = (raw % 8 == 0) ? raw : ((raw + 7) / 8) * 8;
    if (p > 524288) p = 524288;
    const int ind = (raw <= p) ? 1 : 0;

    for (int d = 0; d < 4; ++d) cfg.res[s][d] = (float)res[d];
    if (ind) {
      cfg.key[s][0] = 1u;
      cfg.key[s][1] = (uint32_t)(res[0] + 1);
      cfg.key[s][2] = (uint32_t)((res[0] + 1) * (res[1] + 1));
      cfg.key[s][3] = (uint32_t)((res[0] + 1) * (res[1] + 1) * (res[2] + 1));
    } else {
      for (int d = 0; d < 4; ++d) cfg.key[s][d] = primes[d];
    }
    cfg.mask[s]   = (uint32_t)(p - 1);
    cfg.offset[s] = (int)total;
    cfg.dense[s]  = ind;
    total += p * 2;
  }
}

static inline size_t align_up(size_t v, size_t a) { return (v + a - 1) & ~(a - 1); }

extern "C" void kernel_launch(void* const* d_in, const int* in_sizes, int n_in,
                              void* d_out, int out_size, void* d_ws, size_t ws_size,
                              hipStream_t stream)
{
  const float* xyzt  = (const float*)d_in[0];
  const float* table = (const float*)d_in[1];
  float*       out   = (float*)d_out;
  const int N = in_sizes[0] / 4;

  Cfg cfg;
  build_cfg(cfg);

  const int qblocks = (N + TPB - 1) / TPB;

  // workspace layout
  size_t off = 0;
  const size_t perm_off = off;             off = align_up(off + (size_t)N * 4, 256);
  const size_t hist_off = off;             off = align_up(off + (size_t)BINS * 4, 256);
  const size_t cur_off  = off;             off = align_up(off + (size_t)BINS * 4, 256);
  const size_t cs_off   = align_up(off, 16);  off = cs_off + (size_t)N * 16;
  const size_t ws_off   = align_up(off, 16);
  const size_t need_sorted = ws_off + (size_t)N * NSCALES * sizeof(float2);
  const size_t need_plain  = (size_t)N * NSCALES * sizeof(float2);

  char* wsb = (char*)d_ws;

  if (ws_size >= need_sorted) {
    uint32_t* perm = (uint32_t*)(wsb + perm_off);
    uint32_t* hist = (uint32_t*)(wsb + hist_off);
    uint32_t* cur  = (uint32_t*)(wsb + cur_off);
    float*    csrt = (float*)(wsb + cs_off);
    float2*   ws   = (float2*)(wsb + ws_off);

    hipMemsetAsync(hist, 0, (size_t)BINS * 4, stream);
    hipLaunchKernelGGL(hist_kernel, dim3(qblocks), dim3(TPB), 0, stream,
                       xyzt, hist, N);
    hipLaunchKernelGGL(scan_kernel, dim3(1), dim3(1024), 0, stream, hist, cur);
    hipLaunchKernelGGL(scatter_kernel, dim3(qblocks), dim3(TPB), 0, stream,
                       xyzt, cur, perm, csrt, N);
    hipLaunchKernelGGL(gather_kernel, dim3(qblocks, NSCALES), dim3(TPB), 0,
                       stream, csrt, table, ws, N, 0, cfg);
    const int tblocks = (N + QPB - 1) / QPB;
    hipLaunchKernelGGL(transpose_perm, dim3(tblocks), dim3(TPB), 0, stream,
                       ws, perm, out, N);
  } else if (ws_size >= need_plain) {
    float2* ws = (float2*)d_ws;
    hipLaunchKernelGGL(gather_kernel, dim3(qblocks, NSCALES), dim3(TPB), 0,
                       stream, xyzt, table, ws, N, 0, cfg);
    hipLaunchKernelGGL(transpose_kernel, dim3(qblocks), dim3(TPB), 0,
                       stream, ws, out, N);
  } else {
    hipLaunchKernelGGL(hashenc_fused, dim3(qblocks), dim3(TPB), 0,
                       stream, (const float4*)xyzt, table, out, N, cfg);
  }
}